// Round 5
// baseline (451.528 us; speedup 1.0000x reference)
//
#include <hip/hip_runtime.h>

// ---------- types ----------
typedef __bf16 bf16x8 __attribute__((ext_vector_type(8)));
typedef float  floatx4 __attribute__((ext_vector_type(4)));
typedef unsigned short ushortx8 __attribute__((ext_vector_type(8)));
typedef unsigned short ushortx2 __attribute__((ext_vector_type(2)));

__device__ __forceinline__ float bf2f(unsigned short u) {
    return __uint_as_float(((unsigned)u) << 16);
}
__device__ __forceinline__ unsigned short f2bf(float f) {
    unsigned u = __float_as_uint(f);
    return (unsigned short)((u + 0x7FFFu + ((u >> 16) & 1u)) >> 16);
}

// async global->LDS, 16B per lane; lds dest = wave-uniform base + lane*16
__device__ __forceinline__ void gload_lds16(const unsigned short* g, unsigned short* l) {
    __builtin_amdgcn_global_load_lds(
        (const __attribute__((address_space(1))) void*)g,
        (__attribute__((address_space(3))) void*)l, 16, 0, 0);
}

// ---------- helpers ----------
__global__ void transpose_cvt_kernel(const float* __restrict__ in,
                                     unsigned short* __restrict__ out,
                                     int K, int N) {
    int idx = blockIdx.x * blockDim.x + threadIdx.x;
    if (idx >= K * N) return;
    int k = idx / N, n = idx - k * N;
    out[n * K + k] = f2bf(in[idx]);
}

__global__ void init_head_kernel(int* __restrict__ head, int n) {
    int i = blockIdx.x * blockDim.x + threadIdx.x;
    if (i < n) head[i] = -1;
}

// two lists per dst: head[mask*Nn + dst]
__global__ void build_list_kernel(const int* __restrict__ ei, const int* __restrict__ em,
                                  int E, int Nn,
                                  int* __restrict__ head, int* __restrict__ nxt) {
    int e = blockIdx.x * blockDim.x + threadIdx.x;
    if (e >= E) return;
    int d = ei[E + e];
    int m = em[e];
    nxt[e] = atomicExch(&head[m * Nn + d], e);
}

// ---------- pipelined GEMM: C[M,N] = A[M,K] @ B[K,N] + bias ----------
// A row-major (fp32 if AF32, else bf16), Bt = B^T (N x K) bf16.
// BM=128, BN=NI*32, BK=64. Single barrier per K-iter: B-tile double-buffered in
// LDS via global_load_lds (stage k+1 issued before compute k -> drain overlaps a
// full MFMA phase); A-fragments loaded per-wave direct global->VGPR (no barrier
// dependency), with optional fused fp32->bf16 convert.
template<int NI, bool AF32>
__global__ __launch_bounds__(256, 3) void gemm_direct(
    const void* __restrict__ Ap,
    const unsigned short* __restrict__ Bt,
    const float* __restrict__ bias,
    unsigned short* __restrict__ C,
    int M, int N, int K)
{
    constexpr int GB = 2 * NI;       // B groups per k-half
    constexpr int NGROUP = 4 * NI;   // groups per LDS buffer
    __shared__ unsigned short Sh[2 * NGROUP * 512];   // NI=4: 32 KB, NI=2: 16 KB

    const int tid  = threadIdx.x;
    const int lane = tid & 63;
    const int wave = tid >> 6;

    // XCD-aware swizzle: blocks sharing an A-row-tile land on one XCD (ids = same mod 8)
    int bx, by;
    {
        int gx = gridDim.x;
        int id = blockIdx.y * gx + blockIdx.x;
        int rows8 = gridDim.y & ~7;
        int full = rows8 * gx;
        if (id < full) {
            int per = gx * 8;
            int t = id / per, r = id - t * per;
            bx = r >> 3; by = t * 8 + (r & 7);
        } else {
            int t = id - full;
            by = rows8 + t / gx; bx = t - (t / gx) * gx;
        }
    }
    const int bM = by * 128;
    const int bN = bx * (NI * 32);
    const int wm = (wave >> 1) * 64;
    const int wn = (wave & 1) * (NI * 16);
    const int q    = lane >> 4;
    const int mrow = lane & 15;

    // A row pointers per mi (clamped; dup rows never stored)
    const char* pa[4];
    constexpr int esz = AF32 ? 4 : 2;
#pragma unroll
    for (int mi = 0; mi < 4; mi++) {
        int r = bM + wm + mi * 16 + mrow; if (r >= M) r = M - 1;
        pa[mi] = (const char*)Ap + ((size_t)r * K + q * 8) * esz;
    }
    // B stage source pointers (frag order: group g holds B[n=g*16+mrow][k=s*32+q*8..])
    const unsigned short* pb[NI];
#pragma unroll
    for (int c = 0; c < NI; c++) {
        int gg = wave + 4 * c;
        int g = gg & (GB - 1), s = gg / GB;
        int rB = bN + g * 16 + mrow;
        pb[c] = Bt + (size_t)rB * K + s * 32 + q * 8;
    }

    floatx4 acc[4][NI];
#pragma unroll
    for (int i = 0; i < 4; i++)
#pragma unroll
        for (int j = 0; j < NI; j++) acc[i][j] = (floatx4)(0.0f);

    auto stage = [&](int k) {
        unsigned short* base = Sh + (size_t)(k & 1) * NGROUP * 512;
        int kt = k * 64;
#pragma unroll
        for (int c = 0; c < NI; c++)
            gload_lds16(pb[c] + kt, base + (wave + 4 * c) * 512);
    };

    const int KI = K >> 6;
    stage(0);
    for (int k = 0; k < KI; k++) {
        __syncthreads();                       // drain: B_k arrived; buffer-swap safe
        if (k + 1 < KI) stage(k + 1);          // async into other buffer, lands during compute
        const int kt = k * 64;

        bf16x8 af[2][4];
#pragma unroll
        for (int s = 0; s < 2; s++)
#pragma unroll
            for (int mi = 0; mi < 4; mi++) {
                if (AF32) {
                    const float* p = (const float*)pa[mi] + kt + s * 32;
                    float4 u0 = *(const float4*)p;
                    float4 u1 = *(const float4*)(p + 4);
                    bf16x8 t;
                    t[0] = (__bf16)u0.x; t[1] = (__bf16)u0.y;
                    t[2] = (__bf16)u0.z; t[3] = (__bf16)u0.w;
                    t[4] = (__bf16)u1.x; t[5] = (__bf16)u1.y;
                    t[6] = (__bf16)u1.z; t[7] = (__bf16)u1.w;
                    af[s][mi] = t;
                } else {
                    af[s][mi] = *(const bf16x8*)((const unsigned short*)pa[mi] + (kt + s * 32) * 1);
                }
            }

        const unsigned short* base = Sh + (size_t)(k & 1) * NGROUP * 512;
#pragma unroll
        for (int s = 0; s < 2; s++) {
            bf16x8 bfv[NI];
#pragma unroll
            for (int ni = 0; ni < NI; ni++)
                bfv[ni] = *(const bf16x8*)(base + (s * GB + (wave & 1) * NI + ni) * 512 + lane * 8);
#pragma unroll
            for (int mi = 0; mi < 4; mi++)
#pragma unroll
                for (int ni = 0; ni < NI; ni++)
                    acc[mi][ni] = __builtin_amdgcn_mfma_f32_16x16x32_bf16(
                        af[s][mi], bfv[ni], acc[mi][ni], 0, 0, 0);
        }
    }

    // ---- epilogue: per-wave LDS repack (region = buf0, disjoint from last-iter buf1) ----
    // acc C/D layout: col = mrow, row = q*4 + r  (m89/m91-verified)
    constexpr int W = NI * 16;
    unsigned short* lbuf = Sh + wave * 32 * W;
    float bv[NI];
#pragma unroll
    for (int ni = 0; ni < NI; ni++) bv[ni] = bias[bN + wn + ni * 16 + mrow];

#pragma unroll
    for (int p = 0; p < 2; p++) {
#pragma unroll
        for (int mh = 0; mh < 2; mh++) {
            int mi = 2 * p + mh;
#pragma unroll
            for (int ni = 0; ni < NI; ni++)
#pragma unroll
                for (int r = 0; r < 4; r++)
                    lbuf[(mh * 16 + q * 4 + r) * W + ni * 16 + mrow] =
                        f2bf(acc[mi][ni][r] + bv[ni]);
        }
        constexpr int LPR = W / 8;        // lanes per row
        constexpr int RPI = 64 / LPR;     // rows per store instr
#pragma unroll
        for (int i = 0; i < 32 / RPI; i++) {
            int prow = i * RPI + lane / LPR;
            int pcol = (lane % LPR) * 8;
            int grow = bM + wm + p * 32 + prow;
            if (grow < M)
                *(ushortx8*)(C + (size_t)grow * N + bN + wn + pcol) =
                    *(const ushortx8*)&lbuf[prow * W + pcol];
        }
    }
}

// ---------- propagate step: one wave per destination node, per-mask edge list ----------
template <int VEC> struct VecT;
template <> struct VecT<8> { typedef ushortx8 type; };
template <> struct VecT<2> { typedef ushortx2 type; };

template <int VEC, bool ADD_SELF, bool RELU, bool OUT_F32>
__global__ __launch_bounds__(256) void prop_step_kernel(
    const unsigned short* __restrict__ cur,  // bf16 [Nn, F]
    void* __restrict__ outp,                 // bf16 or fp32 [Nn, F]
    const int* __restrict__ head,            // per-mask heads (pre-offset)
    const int* __restrict__ nxt,
    const int* __restrict__ esrc,
    int Nn)
{
    typedef typename VecT<VEC>::type VT;
    const int w = blockIdx.x * 4 + (threadIdx.x >> 6);
    if (w >= Nn) return;
    const int lane = threadIdx.x & 63;
    const int F = VEC * 64;
    const size_t off = (size_t)w * F + lane * VEC;

    float acc[VEC];
    if (ADD_SELF) {
        VT v = *(const VT*)(cur + off);
#pragma unroll
        for (int i = 0; i < VEC; i++) acc[i] = bf2f(v[i]);
    } else {
#pragma unroll
        for (int i = 0; i < VEC; i++) acc[i] = 0.0f;
    }

    for (int e = head[w]; e >= 0; e = nxt[e]) {
        int s = esrc[e];
        VT v = *(const VT*)(cur + (size_t)s * F + lane * VEC);
#pragma unroll
        for (int i = 0; i < VEC; i++) acc[i] += bf2f(v[i]);
    }

#pragma unroll
    for (int i = 0; i < VEC; i++)
        if (RELU && acc[i] < 0.0f) acc[i] = 0.0f;

    if (OUT_F32) {
        float* out = (float*)outp;
        float2 o2;
#pragma unroll
        for (int i = 0; i < VEC; i += 2) {
            o2.x = acc[i]; o2.y = acc[i + 1];
            *(float2*)(out + off + i) = o2;
        }
    } else {
        VT o;
#pragma unroll
        for (int i = 0; i < VEC; i++) o[i] = f2bf(acc[i]);
        *(VT*)((unsigned short*)outp + off) = o;
    }
}

// ---------- launch ----------
extern "C" void kernel_launch(void* const* d_in, const int* in_sizes, int n_in,
                              void* d_out, int out_size, void* d_ws, size_t ws_size,
                              hipStream_t stream)
{
    const float* x  = (const float*)d_in[0];       // [Nn, 512] fp32
    const int*   ei = (const int*)d_in[1];         // [2, E] int32
    const int*   em = (const int*)d_in[2];         // [E]
    const float* W1 = (const float*)d_in[5];       // [512,512]
    const float* b1 = (const float*)d_in[6];       // [512]
    const float* W2 = (const float*)d_in[7];       // [512,128]
    const float* b2 = (const float*)d_in[8];       // [128]

    const int FIN = 512, FOUT = 128;
    const int Nn = in_sizes[0] / FIN;   // 60000
    const int E  = in_sizes[2];         // 160000

    char* ws = (char*)d_ws;
    size_t off = 0;
    auto alloc = [&](size_t bytes) -> char* {
        char* p = ws + off;
        off += (bytes + 255) & ~(size_t)255;
        return p;
    };
    unsigned short* W1t = (unsigned short*)alloc((size_t)FIN * FIN * 2);
    unsigned short* W2t = (unsigned short*)alloc((size_t)FIN * FOUT * 2);
    unsigned short* h1  = (unsigned short*)alloc((size_t)Nn * FIN * 2); // reused as B1
    unsigned short* A1  = (unsigned short*)alloc((size_t)Nn * FIN * 2);
    unsigned short* h2  = (unsigned short*)alloc((size_t)Nn * FOUT * 2);
    unsigned short* A2  = (unsigned short*)alloc((size_t)Nn * FOUT * 2);
    int* head = (int*)alloc((size_t)2 * Nn * 4);   // [2][Nn]
    int* nxt  = (int*)alloc((size_t)E * 4);
    (void)ws_size; (void)n_in; (void)out_size;

    // 1) weights -> B^T bf16
    transpose_cvt_kernel<<<(FIN * FIN + 255) / 256, 256, 0, stream>>>(W1, W1t, FIN, FIN);
    transpose_cvt_kernel<<<(FIN * FOUT + 255) / 256, 256, 0, stream>>>(W2, W2t, FIN, FOUT);

    // 2) per-(mask,dst) linked lists
    init_head_kernel<<<(2 * Nn + 255) / 256, 256, 0, stream>>>(head, 2 * Nn);
    build_list_kernel<<<(E + 255) / 256, 256, 0, stream>>>(ei, em, E, Nn, head, nxt);

    const int gy = (Nn + 127) / 128;

    // 3) h1 = x @ W1 + b1  (fused fp32->bf16 A-convert)
    gemm_direct<4, true><<<dim3(FIN / 128, gy), 256, 0, stream>>>(
        (const void*)x, W1t, b1, h1, Nn, FIN, FIN);

    // 4) P1: A1 = S0(h1);  B1 = relu(A1 + S1(A1))
    {
        int grid = (Nn + 3) / 4;
        prop_step_kernel<8, false, false, false><<<grid, 256, 0, stream>>>(h1, A1, head,      nxt, ei, Nn);
        prop_step_kernel<8, true,  true,  false><<<grid, 256, 0, stream>>>(A1, h1, head + Nn, nxt, ei, Nn);
    }

    // 5) h2 = B1 @ W2 + b2  (BN=64 -> 2x grid for occupancy)
    gemm_direct<2, false><<<dim3(FOUT / 64, gy), 256, 0, stream>>>(
        (const void*)h1, W2t, b2, h2, Nn, FOUT, FIN);

    // 6) P2: A2 = S0(h2);  out = A2 + S1(A2)  (fp32)
    {
        int grid = (Nn + 3) / 4;
        prop_step_kernel<2, false, false, false><<<grid, 256, 0, stream>>>(h2, A2, head,      nxt, ei, Nn);
        prop_step_kernel<2, true,  false, true ><<<grid, 256, 0, stream>>>(A2, d_out, head + Nn, nxt, ei, Nn);
    }
}

// Round 6
// 419.267 us; speedup vs baseline: 1.0769x; 1.0769x over previous
//
#include <hip/hip_runtime.h>

// ---------- types ----------
typedef __bf16 bf16x8 __attribute__((ext_vector_type(8)));
typedef float  floatx4 __attribute__((ext_vector_type(4)));
typedef unsigned short ushortx8 __attribute__((ext_vector_type(8)));
typedef unsigned short ushortx2 __attribute__((ext_vector_type(2)));

__device__ __forceinline__ float bf2f(unsigned short u) {
    return __uint_as_float(((unsigned)u) << 16);
}
__device__ __forceinline__ unsigned short f2bf(float f) {
    unsigned u = __float_as_uint(f);
    return (unsigned short)((u + 0x7FFFu + ((u >> 16) & 1u)) >> 16);
}

// async global->LDS, 16B per lane; lds dest = wave-uniform base + lane*16
__device__ __forceinline__ void gload_lds16(const void* g, unsigned short* l) {
    __builtin_amdgcn_global_load_lds(
        (const __attribute__((address_space(1))) void*)g,
        (__attribute__((address_space(3))) void*)l, 16, 0, 0);
}

// ---------- helpers ----------
__global__ void transpose_cvt_kernel(const float* __restrict__ in,
                                     unsigned short* __restrict__ out,
                                     int K, int N) {
    int idx = blockIdx.x * blockDim.x + threadIdx.x;
    if (idx >= K * N) return;
    int k = idx / N, n = idx - k * N;
    out[n * K + k] = f2bf(in[idx]);
}

__global__ void zero_int_kernel(int* __restrict__ p, int n) {
    int i = blockIdx.x * blockDim.x + threadIdx.x;
    if (i < n) p[i] = 0;
}

// slotted CSR: per (mask,dst) contiguous src list, stride 32
#define ADJ_STRIDE 32
__global__ void build_csr_kernel(const int* __restrict__ ei, const int* __restrict__ em,
                                 int E, int Nn,
                                 int* __restrict__ cnt, int* __restrict__ adj) {
    int e = blockIdx.x * blockDim.x + threadIdx.x;
    if (e >= E) return;
    int d = ei[E + e];
    int m = em[e];
    int s = ei[e];
    int idx = m * Nn + d;
    int slot = atomicAdd(&cnt[idx], 1);
    if (slot < ADJ_STRIDE) adj[(size_t)idx * ADJ_STRIDE + slot] = s;
}

// ---------- GEMM: C[M,N] = A[M,K] @ B[K,N] + bias ----------
// R4-proven structure: both operands staged via global_load_lds in MFMA-fragment
// order, BK=64, 2 barriers/iter, XCD swizzle, LDS-repack epilogue.
// AF32: A is fp32, staged raw (4 floats/lane/group) and converted after ds_read
// (fuses the fp32->bf16 pass into GEMM1). BN = NI*32.
template<int NI, bool AF32>
__global__ __launch_bounds__(256) void gemm_glds(
    const void* __restrict__ Ap,             // M x K (fp32 if AF32 else bf16)
    const unsigned short* __restrict__ Bt,   // N x K bf16
    const float* __restrict__ bias,          // N fp32
    unsigned short* __restrict__ C,          // M x N bf16
    int M, int N, int K)
{
    constexpr int GB = 2 * NI;               // B n-groups per k-half
    constexpr int AGROUPS = AF32 ? 32 : 16;  // A staging groups (1 KB each)
    constexpr int BGROUPS = 4 * NI;
    __shared__ unsigned short Sh[(AGROUPS + BGROUPS) * 512];  // GEMM1: 48 KB
    unsigned short* Abase = Sh;
    unsigned short* Bbase = Sh + AGROUPS * 512;

    const int tid  = threadIdx.x;
    const int lane = tid & 63;
    const int wave = tid >> 6;

    // XCD-aware swizzle: blocks sharing an A-row-tile -> same id mod 8 -> same XCD
    int bx, by;
    {
        int gx = gridDim.x;
        int id = blockIdx.y * gx + blockIdx.x;
        int rows8 = gridDim.y & ~7;
        int full = rows8 * gx;
        if (id < full) {
            int per = gx * 8;
            int t = id / per, r = id - t * per;
            bx = r >> 3; by = t * 8 + (r & 7);
        } else {
            int t = id - full;
            by = rows8 + t / gx; bx = t - (t / gx) * gx;
        }
    }
    const int bM = by * 128;
    const int bN = bx * (NI * 32);
    const int wm = (wave >> 1) * 64;
    const int wn = (wave & 1) * (NI * 16);
    const int q    = lane >> 4;
    const int mrow = lane & 15;

    // ---- staging source pointers ----
    // A fp32: group gg = c*8+g holds A[bM+g*16+r][kt + c*16 + (l>>4)*4 ..+3]
    const float* pA32[8];
    // A bf16: group gg = s*8+g holds A[bM+g*16+r][kt + s*32 + (l>>4)*8 ..+7]
    const unsigned short* pA16[4];
    if (AF32) {
#pragma unroll
        for (int j = 0; j < 8; j++) {
            int gg = wave + 4 * j;
            int g = gg & 7, c = gg >> 3;
            int r = bM + g * 16 + mrow; if (r >= M) r = M - 1;  // dup rows never stored
            pA32[j] = (const float*)Ap + (size_t)r * K + c * 16 + q * 4;
        }
    } else {
#pragma unroll
        for (int j = 0; j < 4; j++) {
            int gg = wave + 4 * j;
            int g = gg & 7, s = gg >> 3;
            int r = bM + g * 16 + mrow; if (r >= M) r = M - 1;
            pA16[j] = (const unsigned short*)Ap + (size_t)r * K + s * 32 + q * 8;
        }
    }
    const unsigned short* pB[NI];
#pragma unroll
    for (int c = 0; c < NI; c++) {
        int gg = wave + 4 * c;
        int g = gg & (GB - 1), s = gg / GB;
        pB[c] = Bt + (size_t)(bN + g * 16 + mrow) * K + s * 32 + q * 8;
    }

    floatx4 acc[4][NI];
#pragma unroll
    for (int i = 0; i < 4; i++)
#pragma unroll
        for (int j = 0; j < NI; j++) acc[i][j] = (floatx4)(0.0f);

    const int KI = K >> 6;
    for (int k = 0; k < KI; k++) {
        const int kt = k * 64;
        if (AF32) {
#pragma unroll
            for (int j = 0; j < 8; j++)
                gload_lds16(pA32[j] + kt, Abase + (wave + 4 * j) * 512);
        } else {
#pragma unroll
            for (int j = 0; j < 4; j++)
                gload_lds16(pA16[j] + kt, Abase + (wave + 4 * j) * 512);
        }
#pragma unroll
        for (int c = 0; c < NI; c++)
            gload_lds16(pB[c] + kt, Bbase + (wave + 4 * c) * 512);
        __syncthreads();   // drain async LDS loads + barrier

        bf16x8 af[2][4];
        if (AF32) {
            // frag k = s*32+q*8+j -> chunk c = 2s+(q>>1), kq = 2(q&1)(+1)
#pragma unroll
            for (int s = 0; s < 2; s++)
#pragma unroll
                for (int mi = 0; mi < 4; mi++) {
                    const unsigned short* ap = Abase
                        + ((2 * s + (q >> 1)) * 8 + ((wave >> 1) * 4 + mi)) * 512
                        + (2 * (q & 1) * 16 + mrow) * 8;
                    floatx4 u0 = *(const floatx4*)ap;
                    floatx4 u1 = *(const floatx4*)(ap + 128);
                    bf16x8 t;
                    t[0] = (__bf16)u0[0]; t[1] = (__bf16)u0[1];
                    t[2] = (__bf16)u0[2]; t[3] = (__bf16)u0[3];
                    t[4] = (__bf16)u1[0]; t[5] = (__bf16)u1[1];
                    t[6] = (__bf16)u1[2]; t[7] = (__bf16)u1[3];
                    af[s][mi] = t;
                }
        } else {
#pragma unroll
            for (int s = 0; s < 2; s++)
#pragma unroll
                for (int mi = 0; mi < 4; mi++)
                    af[s][mi] = *(const bf16x8*)(Abase
                        + (s * 8 + (wave >> 1) * 4 + mi) * 512 + lane * 8);
        }

#pragma unroll
        for (int s = 0; s < 2; s++) {
            bf16x8 bfv[NI];
#pragma unroll
            for (int ni = 0; ni < NI; ni++)
                bfv[ni] = *(const bf16x8*)(Bbase
                    + (s * GB + (wave & 1) * NI + ni) * 512 + lane * 8);
#pragma unroll
            for (int mi = 0; mi < 4; mi++)
#pragma unroll
                for (int ni = 0; ni < NI; ni++)
                    acc[mi][ni] = __builtin_amdgcn_mfma_f32_16x16x32_bf16(
                        af[s][mi], bfv[ni], acc[mi][ni], 0, 0, 0);
        }
        __syncthreads();   // protect LDS before next staging
    }

    // ---- epilogue: per-wave LDS repack -> 16B/lane coalesced stores ----
    // acc C/D layout: col = mrow, row = q*4 + r  (m89/m91-verified)
    constexpr int W = NI * 16;
    unsigned short* lbuf = Sh + wave * 32 * W;
    float bv[NI];
#pragma unroll
    for (int ni = 0; ni < NI; ni++) bv[ni] = bias[bN + wn + ni * 16 + mrow];

#pragma unroll
    for (int p = 0; p < 2; p++) {
#pragma unroll
        for (int mh = 0; mh < 2; mh++) {
            int mi = 2 * p + mh;
#pragma unroll
            for (int ni = 0; ni < NI; ni++)
#pragma unroll
                for (int r = 0; r < 4; r++)
                    lbuf[(mh * 16 + q * 4 + r) * W + ni * 16 + mrow] =
                        f2bf(acc[mi][ni][r] + bv[ni]);
        }
        constexpr int LPR = W / 8;
        constexpr int RPI = 64 / LPR;
#pragma unroll
        for (int i = 0; i < 32 / RPI; i++) {
            int prow = i * RPI + lane / LPR;
            int pcol = (lane % LPR) * 8;
            int grow = bM + wm + p * 32 + prow;
            if (grow < M)
                *(ushortx8*)(C + (size_t)grow * N + bN + wn + pcol) =
                    *(const ushortx8*)&lbuf[prow * W + pcol];
        }
    }
}

// ---------- propagate step: one wave per destination, slotted-CSR adjacency ----------
template <int VEC> struct VecT;
template <> struct VecT<8> { typedef ushortx8 type; };
template <> struct VecT<2> { typedef ushortx2 type; };

template <int VEC, bool ADD_SELF, bool RELU, bool OUT_F32>
__global__ __launch_bounds__(256) void prop_csr_kernel(
    const unsigned short* __restrict__ cur,  // bf16 [Nn, F]
    void* __restrict__ outp,                 // bf16 or fp32 [Nn, F]
    const int* __restrict__ cnt,             // per-mask counts (pre-offset)
    const int* __restrict__ adj,             // per-mask src lists (pre-offset)
    int Nn)
{
    typedef typename VecT<VEC>::type VT;
    const int w = blockIdx.x * 4 + (threadIdx.x >> 6);
    if (w >= Nn) return;
    const int lane = threadIdx.x & 63;
    const int F = VEC * 64;
    const size_t off = (size_t)w * F + lane * VEC;

    int deg = cnt[w];
    if (deg > ADJ_STRIDE) deg = ADJ_STRIDE;
    const int* lst = adj + (size_t)w * ADJ_STRIDE;

    float acc[VEC];
    if (ADD_SELF) {
        VT v = *(const VT*)(cur + off);
#pragma unroll
        for (int i = 0; i < VEC; i++) acc[i] = bf2f(v[i]);
    } else {
#pragma unroll
        for (int i = 0; i < VEC; i++) acc[i] = 0.0f;
    }

    for (int i = 0; i < deg; i++) {
        int s = lst[i];                      // independent loads: pipelineable
        VT v = *(const VT*)(cur + (size_t)s * F + lane * VEC);
#pragma unroll
        for (int j = 0; j < VEC; j++) acc[j] += bf2f(v[j]);
    }

#pragma unroll
    for (int i = 0; i < VEC; i++)
        if (RELU && acc[i] < 0.0f) acc[i] = 0.0f;

    if (OUT_F32) {
        float* out = (float*)outp;
        float2 o2;
#pragma unroll
        for (int i = 0; i < VEC; i += 2) {
            o2.x = acc[i]; o2.y = acc[i + 1];
            *(float2*)(out + off + i) = o2;
        }
    } else {
        VT o;
#pragma unroll
        for (int i = 0; i < VEC; i++) o[i] = f2bf(acc[i]);
        *(VT*)((unsigned short*)outp + off) = o;
    }
}

// ---------- launch ----------
extern "C" void kernel_launch(void* const* d_in, const int* in_sizes, int n_in,
                              void* d_out, int out_size, void* d_ws, size_t ws_size,
                              hipStream_t stream)
{
    const float* x  = (const float*)d_in[0];       // [Nn, 512] fp32
    const int*   ei = (const int*)d_in[1];         // [2, E] int32
    const int*   em = (const int*)d_in[2];         // [E]
    const float* W1 = (const float*)d_in[5];       // [512,512]
    const float* b1 = (const float*)d_in[6];       // [512]
    const float* W2 = (const float*)d_in[7];       // [512,128]
    const float* b2 = (const float*)d_in[8];       // [128]

    const int FIN = 512, FOUT = 128;
    const int Nn = in_sizes[0] / FIN;   // 60000
    const int E  = in_sizes[2];         // 160000

    char* ws = (char*)d_ws;
    size_t off = 0;
    auto alloc = [&](size_t bytes) -> char* {
        char* p = ws + off;
        off += (bytes + 255) & ~(size_t)255;
        return p;
    };
    unsigned short* W1t = (unsigned short*)alloc((size_t)FIN * FIN * 2);
    unsigned short* W2t = (unsigned short*)alloc((size_t)FIN * FOUT * 2);
    unsigned short* h1  = (unsigned short*)alloc((size_t)Nn * FIN * 2); // reused as B1
    unsigned short* A1  = (unsigned short*)alloc((size_t)Nn * FIN * 2);
    unsigned short* h2  = (unsigned short*)alloc((size_t)Nn * FOUT * 2);
    unsigned short* A2  = (unsigned short*)alloc((size_t)Nn * FOUT * 2);
    int* cnt = (int*)alloc((size_t)2 * Nn * 4);                 // [2][Nn]
    int* adj = (int*)alloc((size_t)2 * Nn * ADJ_STRIDE * 4);    // [2][Nn][32]
    (void)ws_size; (void)n_in; (void)out_size;

    // 1) weights -> B^T bf16
    transpose_cvt_kernel<<<(FIN * FIN + 255) / 256, 256, 0, stream>>>(W1, W1t, FIN, FIN);
    transpose_cvt_kernel<<<(FIN * FOUT + 255) / 256, 256, 0, stream>>>(W2, W2t, FIN, FOUT);

    // 2) slotted CSR
    zero_int_kernel<<<(2 * Nn + 255) / 256, 256, 0, stream>>>(cnt, 2 * Nn);
    build_csr_kernel<<<(E + 255) / 256, 256, 0, stream>>>(ei, em, E, Nn, cnt, adj);

    const int gy = (Nn + 127) / 128;

    // 3) h1 = x @ W1 + b1  (A staged as fp32, converted post-ds_read: no separate cvt pass)
    gemm_glds<4, true><<<dim3(FIN / 128, gy), 256, 0, stream>>>(
        (const void*)x, W1t, b1, h1, Nn, FIN, FIN);

    // 4) P1: A1 = S0(h1);  B1 = relu(A1 + S1(A1))
    {
        int grid = (Nn + 3) / 4;
        prop_csr_kernel<8, false, false, false><<<grid, 256, 0, stream>>>(
            h1, A1, cnt, adj, Nn);
        prop_csr_kernel<8, true, true, false><<<grid, 256, 0, stream>>>(
            A1, h1, cnt + Nn, adj + (size_t)Nn * ADJ_STRIDE, Nn);
    }

    // 5) h2 = B1 @ W2 + b2  (BN=64 -> 938 blocks)
    gemm_glds<2, false><<<dim3(FOUT / 64, gy), 256, 0, stream>>>(
        (const void*)h1, W2t, b2, h2, Nn, FOUT, FIN);

    // 6) P2: A2 = S0(h2);  out = A2 + S1(A2)  (fp32 out)
    {
        int grid = (Nn + 3) / 4;
        prop_csr_kernel<2, false, false, false><<<grid, 256, 0, stream>>>(
            h2, A2, cnt, adj, Nn);
        prop_csr_kernel<2, true, false, true><<<grid, 256, 0, stream>>>(
            A2, d_out, cnt + Nn, adj + (size_t)Nn * ADJ_STRIDE, Nn);
    }
}